// Round 1
// baseline (395.772 us; speedup 1.0000x reference)
//
#include <hip/hip_runtime.h>

typedef __attribute__((ext_vector_type(8))) short short8;
typedef __attribute__((ext_vector_type(4))) float f32x4;
typedef __attribute__((ext_vector_type(4))) unsigned short u16x4;
typedef __attribute__((ext_vector_type(4))) float float4v;

#define AS1 __attribute__((address_space(1)))
#define AS3 __attribute__((address_space(3)))

__device__ __forceinline__ unsigned short f2bf(float f) {
    union { float f; unsigned u; } cv; cv.f = f;
    unsigned u = cv.u;
    unsigned r = (u + 0x7FFFu + ((u >> 16) & 1u)) >> 16;
    return (unsigned short)r;
}

__device__ __forceinline__ void async_load16(const void* g, void* l) {
    __builtin_amdgcn_global_load_lds((const AS1 unsigned*)g, (AS3 unsigned*)l, 16, 0, 0);
}

// ---------------- f32 -> bf16 convert ----------------
__global__ void cvt_bf16(const float* __restrict__ in, unsigned short* __restrict__ out, int n4) {
    int i = blockIdx.x * blockDim.x + threadIdx.x;
    if (i >= n4) return;
    float4v v = ((const float4v*)in)[i];
    u16x4 o;
    o[0] = f2bf(v[0]); o[1] = f2bf(v[1]); o[2] = f2bf(v[2]); o[3] = f2bf(v[3]);
    ((u16x4*)out)[i] = o;
}

// ---------------- GEMM: C[M,N] = A[M,K] * B[N,K]^T + bias ----------------
// m97 structure: 128x128 tile, BK=32, 4 waves (2x2), global_load_lds width 16.
template<bool OUT_BF16>
__global__ void gemm_bt(const unsigned short* __restrict__ A,
                        const unsigned short* __restrict__ B,
                        const float* __restrict__ bias,
                        void* __restrict__ Cout,
                        int M, int N, int K) {
    __shared__ __align__(16) unsigned short As[128 * 32];
    __shared__ __align__(16) unsigned short Bs[128 * 32];
    const int tid  = threadIdx.x;
    const int wid  = tid >> 6;
    const int lane = tid & 63;
    const int lg = lane >> 4, lr = lane & 15;
    const int wr = wid >> 1, wc = wid & 1;
    const int m0 = blockIdx.x * 128;
    const int n0 = blockIdx.y * 128;

    f32x4 acc[4][4] = {};

    for (int kt = 0; kt < K; kt += 32) {
        #pragma unroll
        for (int r = 0; r < 2; ++r) {
            int cb = r * 4 + wid;            // chunk-block 0..7 (1KB each)
            int chunk = cb * 64 + lane;      // 0..511, 8 elems each
            int row = chunk >> 2;            // 0..127
            int col = (chunk & 3) * 8;       // 0,8,16,24
            async_load16(&A[(size_t)(m0 + row) * K + kt + col], (char*)As + cb * 1024);
            async_load16(&B[(size_t)(n0 + row) * K + kt + col], (char*)Bs + cb * 1024);
        }
        __syncthreads();
        short8 af[4], bfr[4];
        #pragma unroll
        for (int m = 0; m < 4; ++m)
            af[m] = *(const short8*)&As[(wr * 64 + m * 16 + lr) * 32 + lg * 8];
        #pragma unroll
        for (int n = 0; n < 4; ++n)
            bfr[n] = *(const short8*)&Bs[(wc * 64 + n * 16 + lr) * 32 + lg * 8];
        #pragma unroll
        for (int m = 0; m < 4; ++m)
            #pragma unroll
            for (int n = 0; n < 4; ++n)
                acc[m][n] = __builtin_amdgcn_mfma_f32_16x16x32_bf16(af[m], bfr[n], acc[m][n], 0, 0, 0);
        __syncthreads();
    }

    #pragma unroll
    for (int n = 0; n < 4; ++n) {
        int cc = n0 + wc * 64 + n * 16 + lr;
        float bv = bias[cc];
        #pragma unroll
        for (int m = 0; m < 4; ++m) {
            #pragma unroll
            for (int r = 0; r < 4; ++r) {
                int rr = m0 + wr * 64 + m * 16 + lg * 4 + r;
                float val = acc[m][n][r] + bv;
                if (OUT_BF16)
                    ((unsigned short*)Cout)[(size_t)rr * N + cc] = f2bf(val);
                else
                    ((float*)Cout)[(size_t)rr * N + cc] = val;
            }
        }
    }
}

// ---------------- flash attention (causal) ----------------
// 1 wave per (b, h, 16 q-rows). KV tiles of 32. Online softmax in C-layout.
#define T_SEQ 2048
#define C_EMB 1024
#define HD    64

__global__ __launch_bounds__(64) void attn_fwd(const unsigned short* __restrict__ Q,
                                               const unsigned short* __restrict__ Kt,
                                               const unsigned short* __restrict__ V,
                                               unsigned short* __restrict__ Y) {
    const int lane = threadIdx.x;
    const int lg = lane >> 4, lr = lane & 15;
    const int q0 = blockIdx.x * 16;
    const int h  = blockIdx.y;
    const int b  = blockIdx.z;
    const size_t base = ((size_t)b * T_SEQ) * C_EMB + (size_t)h * HD;

    __shared__ __align__(16) unsigned short Pl[16 * 40];  // padded stride 40 elems
    __shared__ __align__(16) unsigned short Vs[32 * 64];

    // Q A-fragments: lane holds Q[q0 + lr][s*32 + lg*8 .. +8)
    short8 qf[2];
    #pragma unroll
    for (int s = 0; s < 2; ++s)
        qf[s] = *(const short8*)&Q[base + (size_t)(q0 + lr) * C_EMB + s * 32 + lg * 8];

    f32x4 o[4] = {};
    float mrow[4], lsum[4];
    #pragma unroll
    for (int r = 0; r < 4; ++r) { mrow[r] = -1e30f; lsum[r] = 0.0f; }

    const int ntiles = (q0 + 15) / 32 + 1;
    for (int t = 0; t < ntiles; ++t) {
        const int kv0 = t * 32;
        // S = Q * K^T  (two 16-col fragments)
        f32x4 sacc[2] = {};
        #pragma unroll
        for (int c = 0; c < 2; ++c)
            #pragma unroll
            for (int s = 0; s < 2; ++s) {
                short8 kf = *(const short8*)&Kt[base + (size_t)(kv0 + c * 16 + lr) * C_EMB + s * 32 + lg * 8];
                sacc[c] = __builtin_amdgcn_mfma_f32_16x16x32_bf16(qf[s], kf, sacc[c], 0, 0, 0);
            }
        // stage V[32][64] into LDS (coalesced 16B)
        #pragma unroll
        for (int i = 0; i < 4; ++i) {
            int chunk = i * 64 + lane;
            int row = chunk >> 3;
            int col = (chunk & 7) * 8;
            *(short8*)&Vs[row * 64 + col] = *(const short8*)&V[base + (size_t)(kv0 + row) * C_EMB + col];
        }
        // scale + causal mask (C-layout: row = lg*4+r, col = c*16+lr)
        float sv[2][4];
        #pragma unroll
        for (int c = 0; c < 2; ++c)
            #pragma unroll
            for (int r = 0; r < 4; ++r) {
                float x = sacc[c][r] * 0.125f;
                int qi = q0 + lg * 4 + r;
                int ki = kv0 + c * 16 + lr;
                sv[c][r] = (ki <= qi) ? x : -1e30f;
            }
        // row max over 32 cols: elementwise then 16-lane shuffle reduce
        float rmax[4];
        #pragma unroll
        for (int r = 0; r < 4; ++r) rmax[r] = fmaxf(sv[0][r], sv[1][r]);
        #pragma unroll
        for (int off = 8; off; off >>= 1)
            #pragma unroll
            for (int r = 0; r < 4; ++r)
                rmax[r] = fmaxf(rmax[r], __shfl_xor(rmax[r], off, 64));
        float scl[4];
        #pragma unroll
        for (int r = 0; r < 4; ++r) {
            float mn = fmaxf(mrow[r], rmax[r]);
            scl[r] = __expf(mrow[r] - mn);
            mrow[r] = mn;
        }
        float p[2][4];
        #pragma unroll
        for (int c = 0; c < 2; ++c)
            #pragma unroll
            for (int r = 0; r < 4; ++r)
                p[c][r] = __expf(sv[c][r] - mrow[r]);
        float rs[4];
        #pragma unroll
        for (int r = 0; r < 4; ++r) rs[r] = p[0][r] + p[1][r];
        #pragma unroll
        for (int off = 8; off; off >>= 1)
            #pragma unroll
            for (int r = 0; r < 4; ++r)
                rs[r] += __shfl_xor(rs[r], off, 64);
        #pragma unroll
        for (int r = 0; r < 4; ++r) lsum[r] = lsum[r] * scl[r] + rs[r];
        #pragma unroll
        for (int g = 0; g < 4; ++g)
            #pragma unroll
            for (int r = 0; r < 4; ++r)
                o[g][r] *= scl[r];
        // P (C-layout) -> LDS (A-layout source), padded stride 40
        #pragma unroll
        for (int c = 0; c < 2; ++c)
            #pragma unroll
            for (int r = 0; r < 4; ++r)
                Pl[(lg * 4 + r) * 40 + c * 16 + lr] = f2bf(p[c][r]);
        __syncthreads();
        short8 pf = *(const short8*)&Pl[lr * 40 + lg * 8];
        // PV: B-fragment from Vs (scalar reads), 4 d-groups of 16
        #pragma unroll
        for (int g = 0; g < 4; ++g) {
            short8 vf;
            #pragma unroll
            for (int j = 0; j < 8; ++j)
                vf[j] = (short)Vs[(lg * 8 + j) * 64 + g * 16 + lr];
            o[g] = __builtin_amdgcn_mfma_f32_16x16x32_bf16(pf, vf, o[g], 0, 0, 0);
        }
        __syncthreads();
    }

    #pragma unroll
    for (int g = 0; g < 4; ++g)
        #pragma unroll
        for (int r = 0; r < 4; ++r) {
            float val = o[g][r] / lsum[r];
            Y[base + (size_t)(q0 + lg * 4 + r) * C_EMB + g * 16 + lr] = f2bf(val);
        }
}

// ---------------- launcher ----------------
extern "C" void kernel_launch(void* const* d_in, const int* in_sizes, int n_in,
                              void* d_out, int out_size, void* d_ws, size_t ws_size,
                              hipStream_t stream) {
    const float* x  = (const float*)d_in[0];
    const float* Wk = (const float*)d_in[1];
    const float* bk = (const float*)d_in[2];
    const float* Wq = (const float*)d_in[3];
    const float* bq = (const float*)d_in[4];
    const float* Wv = (const float*)d_in[5];
    const float* bv = (const float*)d_in[6];
    const float* Wp = (const float*)d_in[7];
    const float* bp = (const float*)d_in[8];

    const size_t SX = (size_t)8192 * 1024;  // x/q/k/v/y element count
    const size_t SW = (size_t)1024 * 1024;  // weight element count

    char* ws = (char*)d_ws;
    unsigned short* xb  = (unsigned short*)ws; ws += SX * 2;
    unsigned short* Wqb = (unsigned short*)ws; ws += SW * 2;
    unsigned short* Wkb = (unsigned short*)ws; ws += SW * 2;
    unsigned short* Wvb = (unsigned short*)ws; ws += SW * 2;
    unsigned short* Wpb = (unsigned short*)ws; ws += SW * 2;
    unsigned short* qb  = (unsigned short*)ws; ws += SX * 2;
    unsigned short* kb  = (unsigned short*)ws; ws += SX * 2;
    unsigned short* vb  = (unsigned short*)ws; ws += SX * 2;
    unsigned short* yb  = (unsigned short*)ws; ws += SX * 2;

    cvt_bf16<<<(int)(SX / 4 / 256), 256, 0, stream>>>(x,  xb,  (int)(SX / 4));
    cvt_bf16<<<(int)(SW / 4 / 256), 256, 0, stream>>>(Wq, Wqb, (int)(SW / 4));
    cvt_bf16<<<(int)(SW / 4 / 256), 256, 0, stream>>>(Wk, Wkb, (int)(SW / 4));
    cvt_bf16<<<(int)(SW / 4 / 256), 256, 0, stream>>>(Wv, Wvb, (int)(SW / 4));
    cvt_bf16<<<(int)(SW / 4 / 256), 256, 0, stream>>>(Wp, Wpb, (int)(SW / 4));

    dim3 gg(64, 8);  // M/128, N/128
    gemm_bt<true><<<gg, 256, 0, stream>>>(xb, Wqb, bq, qb, 8192, 1024, 1024);
    gemm_bt<true><<<gg, 256, 0, stream>>>(xb, Wkb, bk, kb, 8192, 1024, 1024);
    gemm_bt<true><<<gg, 256, 0, stream>>>(xb, Wvb, bv, vb, 8192, 1024, 1024);

    attn_fwd<<<dim3(T_SEQ / 16, 16, 4), 64, 0, stream>>>(qb, kb, vb, yb);

    gemm_bt<false><<<gg, 256, 0, stream>>>(yb, Wpb, bp, d_out, 8192, 1024, 1024);
}

// Round 2
// 381.563 us; speedup vs baseline: 1.0372x; 1.0372x over previous
//
#include <hip/hip_runtime.h>

typedef __attribute__((ext_vector_type(8))) short short8;
typedef __attribute__((ext_vector_type(4))) float f32x4;
typedef __attribute__((ext_vector_type(4))) unsigned short u16x4;
typedef __attribute__((ext_vector_type(4))) float float4v;

#define AS1 __attribute__((address_space(1)))
#define AS3 __attribute__((address_space(3)))

#define T_SEQ 2048
#define C_EMB 1024
#define NHEAD 16
#define NB    4

__device__ __forceinline__ unsigned short f2bf(float f) {
    union { float f; unsigned u; } cv; cv.f = f;
    unsigned u = cv.u;
    unsigned r = (u + 0x7FFFu + ((u >> 16) & 1u)) >> 16;
    return (unsigned short)r;
}

__device__ __forceinline__ void async_load16(const void* g, void* l) {
    __builtin_amdgcn_global_load_lds((const AS1 unsigned*)g, (AS3 unsigned*)l, 16, 0, 0);
}

// ---------------- f32 -> bf16 convert ----------------
__global__ void cvt_bf16(const float* __restrict__ in, unsigned short* __restrict__ out, int n4) {
    int i = blockIdx.x * blockDim.x + threadIdx.x;
    if (i >= n4) return;
    float4v v = ((const float4v*)in)[i];
    u16x4 o;
    o[0] = f2bf(v[0]); o[1] = f2bf(v[1]); o[2] = f2bf(v[2]); o[3] = f2bf(v[3]);
    ((u16x4*)out)[i] = o;
}

// ---------------- GEMM: C[M,N] = A[M,K] * B[N,K]^T + bias ----------------
// MODE 0: f32 row-major out. MODE 1: bf16 row-major out (scaled).
// MODE 2: bf16 out transposed per-head: vt[((rr>>11)*1024 + cc)*2048 + (rr&2047)]
template<int MODE>
__global__ void gemm_bt(const unsigned short* __restrict__ A,
                        const unsigned short* __restrict__ B,
                        const float* __restrict__ bias,
                        void* __restrict__ Cout,
                        int M, int N, int K, float scale) {
    __shared__ __align__(16) unsigned short As[128 * 32];
    __shared__ __align__(16) unsigned short Bs[128 * 32];
    const int tid  = threadIdx.x;
    const int wid  = tid >> 6;
    const int lane = tid & 63;
    const int lg = lane >> 4, lr = lane & 15;
    const int wr = wid >> 1, wc = wid & 1;
    const int m0 = blockIdx.x * 128;
    const int n0 = blockIdx.y * 128;

    f32x4 acc[4][4] = {};

    for (int kt = 0; kt < K; kt += 32) {
        #pragma unroll
        for (int r = 0; r < 2; ++r) {
            int cb = r * 4 + wid;            // chunk-block 0..7 (1KB each)
            int chunk = cb * 64 + lane;      // 0..511, 8 elems each
            int row = chunk >> 2;            // 0..127
            int col = (chunk & 3) * 8;       // 0,8,16,24
            async_load16(&A[(size_t)(m0 + row) * K + kt + col], (char*)As + cb * 1024);
            async_load16(&B[(size_t)(n0 + row) * K + kt + col], (char*)Bs + cb * 1024);
        }
        __syncthreads();
        short8 af[4], bfr[4];
        #pragma unroll
        for (int m = 0; m < 4; ++m)
            af[m] = *(const short8*)&As[(wr * 64 + m * 16 + lr) * 32 + lg * 8];
        #pragma unroll
        for (int n = 0; n < 4; ++n)
            bfr[n] = *(const short8*)&Bs[(wc * 64 + n * 16 + lr) * 32 + lg * 8];
        #pragma unroll
        for (int m = 0; m < 4; ++m)
            #pragma unroll
            for (int n = 0; n < 4; ++n)
                acc[m][n] = __builtin_amdgcn_mfma_f32_16x16x32_bf16(af[m], bfr[n], acc[m][n], 0, 0, 0);
        __syncthreads();
    }

    #pragma unroll
    for (int n = 0; n < 4; ++n) {
        int cc = n0 + wc * 64 + n * 16 + lr;
        float bv = bias[cc];
        #pragma unroll
        for (int m = 0; m < 4; ++m) {
            int rr0 = m0 + wr * 64 + m * 16 + lg * 4;
            if (MODE == 2) {
                u16x4 pk;
                #pragma unroll
                for (int r = 0; r < 4; ++r)
                    pk[r] = f2bf((acc[m][n][r] + bv) * scale);
                size_t idx = ((size_t)(rr0 >> 11) * 1024 + cc) * 2048 + (rr0 & 2047);
                *(u16x4*)&((unsigned short*)Cout)[idx] = pk;
            } else {
                #pragma unroll
                for (int r = 0; r < 4; ++r) {
                    float val = (acc[m][n][r] + bv) * scale;
                    if (MODE == 1)
                        ((unsigned short*)Cout)[(size_t)(rr0 + r) * N + cc] = f2bf(val);
                    else
                        ((float*)Cout)[(size_t)(rr0 + r) * N + cc] = val;
                }
            }
        }
    }
}

// ---------------- flash attention (causal), 4 waves x 16 q-rows, KVBLK=64 ----------------
// Swapped QK^T (S^T = K*Q^T): softmax lane-local (lane owns q = qw0+lr).
// K staged in LDS with both-sides XOR swizzle; V read from global V^T [b][h][d][t].
__global__ __launch_bounds__(256) void attn_fwd2(const unsigned short* __restrict__ Q,
                                                 const unsigned short* __restrict__ Kg,
                                                 const unsigned short* __restrict__ Vt,
                                                 unsigned short* __restrict__ Y) {
    __shared__ __align__(16) unsigned short Ks[64 * 64];      // 8KB, swizzled
    __shared__ __align__(16) unsigned short Pl[4 * 16 * 64];  // 2KB per wave, swizzled

    const int tid  = threadIdx.x;
    const int w    = tid >> 6;
    const int lane = tid & 63;
    const int lg = lane >> 4, lr = lane & 15;
    const int q0  = blockIdx.x * 64;
    const int h   = blockIdx.y;
    const int b   = blockIdx.z;
    const int qw0 = q0 + w * 16;

    const size_t rowbase = ((size_t)b * T_SEQ) * C_EMB + (size_t)h * 64;   // Q,K,Y
    const size_t vtbase  = ((size_t)b * 1024 + (size_t)h * 64) * T_SEQ;    // Vt [d][t]

    // Q B-fragments (q is already pre-scaled by 0.125 in its GEMM epilogue)
    short8 qf[2];
    #pragma unroll
    for (int s = 0; s < 2; ++s)
        qf[s] = *(const short8*)&Q[rowbase + (size_t)(qw0 + lr) * C_EMB + s * 32 + lg * 8];

    f32x4 o[4] = {};
    float mrun = -1e30f, lrun = 0.0f;

    // staging lane geometry (pre-swizzled global source, linear LDS dest)
    const int srow = lane >> 3;                  // 0..7 within 8-row chunk
    const int scol = ((lane & 7) ^ srow) * 8;    // swizzled column element

    unsigned short* Plw = &Pl[w * 1024];
    const int ntiles = blockIdx.x + 1;

    for (int t = 0; t < ntiles; ++t) {
        const int kv0 = t * 64;
        // ---- stage K tile [64][64] (each wave: 2x 1KB chunks) ----
        #pragma unroll
        for (int i = 0; i < 2; ++i) {
            int cb = w * 2 + i;
            async_load16(&Kg[rowbase + (size_t)(kv0 + cb * 8 + srow) * C_EMB + scol],
                         (char*)Ks + cb * 1024);
        }
        __syncthreads();

        // ---- S^T = K * Q^T : 4 key-blocks x 2 d-chunks ----
        f32x4 sa[4] = {};
        #pragma unroll
        for (int kblk = 0; kblk < 4; ++kblk) {
            int row = kblk * 16 + lr;
            #pragma unroll
            for (int s = 0; s < 2; ++s) {
                short8 kf = *(const short8*)((const char*)Ks + row * 128 +
                                             (((s * 64 + lg * 16)) ^ ((lr & 7) << 4)));
                sa[kblk] = __builtin_amdgcn_mfma_f32_16x16x32_bf16(kf, qf[s], sa[kblk], 0, 0, 0);
            }
        }

        // ---- lane-local online softmax (lane owns q = qw0+lr) ----
        const bool need_mask = (kv0 + 63) > qw0;
        const int qi = qw0 + lr;
        float sv[16];
        #pragma unroll
        for (int kblk = 0; kblk < 4; ++kblk)
            #pragma unroll
            for (int r = 0; r < 4; ++r) {
                float x = sa[kblk][r];
                int ki = kv0 + kblk * 16 + lg * 4 + r;
                sv[kblk * 4 + r] = (need_mask && ki > qi) ? -1e30f : x;
            }
        float tmax = sv[0];
        #pragma unroll
        for (int i = 1; i < 16; ++i) tmax = fmaxf(tmax, sv[i]);
        tmax = fmaxf(tmax, __shfl_xor(tmax, 16));
        tmax = fmaxf(tmax, __shfl_xor(tmax, 32));
        float mn  = fmaxf(mrun, tmax);
        float scl = __expf(mrun - mn);
        mrun = mn;
        float rs = 0.0f;
        #pragma unroll
        for (int i = 0; i < 16; ++i) { float p = __expf(sv[i] - mn); sv[i] = p; rs += p; }
        rs += __shfl_xor(rs, 16);
        rs += __shfl_xor(rs, 32);
        lrun = lrun * scl + rs;
        float scl4[4];
        #pragma unroll
        for (int r = 0; r < 4; ++r) scl4[r] = __shfl(scl, lg * 4 + r);
        #pragma unroll
        for (int g = 0; g < 4; ++g)
            #pragma unroll
            for (int r = 0; r < 4; ++r) o[g][r] *= scl4[r];

        // ---- P^T -> Pl as [q=lr][k] (swizzled), packed b32 writes ----
        #pragma unroll
        for (int kblk = 0; kblk < 4; ++kblk)
            #pragma unroll
            for (int j = 0; j < 2; ++j) {
                unsigned pk = (unsigned)f2bf(sv[kblk * 4 + 2 * j]) |
                              ((unsigned)f2bf(sv[kblk * 4 + 2 * j + 1]) << 16);
                *(unsigned*)((char*)Plw + lr * 128 +
                             ((kblk * 32 + lg * 8 + j * 4) ^ ((lr & 7) << 4))) = pk;
            }
        // ---- read P A-frags (same wave: no barrier needed) ----
        short8 pf[2];
        #pragma unroll
        for (int kc = 0; kc < 2; ++kc)
            pf[kc] = *(const short8*)((const char*)Plw + lr * 128 +
                                      ((kc * 64 + lg * 16) ^ ((lr & 7) << 4)));
        // ---- V^T B-frags from global (contiguous 16B, L2-resident) ----
        short8 vf[4][2];
        #pragma unroll
        for (int g = 0; g < 4; ++g)
            #pragma unroll
            for (int kc = 0; kc < 2; ++kc)
                vf[g][kc] = *(const short8*)&Vt[vtbase + (size_t)(g * 16 + lr) * T_SEQ +
                                                kv0 + kc * 32 + lg * 8];
        #pragma unroll
        for (int g = 0; g < 4; ++g)
            #pragma unroll
            for (int kc = 0; kc < 2; ++kc)
                o[g] = __builtin_amdgcn_mfma_f32_16x16x32_bf16(pf[kc], vf[g][kc], o[g], 0, 0, 0);

        __syncthreads();
    }

    // ---- epilogue: O rows are q = qw0 + lg*4 + r ----
    float l4[4];
    #pragma unroll
    for (int r = 0; r < 4; ++r) l4[r] = __shfl(lrun, lg * 4 + r);
    #pragma unroll
    for (int g = 0; g < 4; ++g)
        #pragma unroll
        for (int r = 0; r < 4; ++r)
            Y[rowbase + (size_t)(qw0 + lg * 4 + r) * C_EMB + g * 16 + lr] =
                f2bf(o[g][r] / l4[r]);
}

// ---------------- launcher ----------------
extern "C" void kernel_launch(void* const* d_in, const int* in_sizes, int n_in,
                              void* d_out, int out_size, void* d_ws, size_t ws_size,
                              hipStream_t stream) {
    const float* x  = (const float*)d_in[0];
    const float* Wk = (const float*)d_in[1];
    const float* bk = (const float*)d_in[2];
    const float* Wq = (const float*)d_in[3];
    const float* bq = (const float*)d_in[4];
    const float* Wv = (const float*)d_in[5];
    const float* bv = (const float*)d_in[6];
    const float* Wp = (const float*)d_in[7];
    const float* bp = (const float*)d_in[8];

    const size_t SX = (size_t)8192 * 1024;  // activation element count
    const size_t SW = (size_t)1024 * 1024;  // weight element count

    char* ws = (char*)d_ws;
    unsigned short* xb  = (unsigned short*)ws; ws += SX * 2;
    unsigned short* Wqb = (unsigned short*)ws; ws += SW * 2;
    unsigned short* Wkb = (unsigned short*)ws; ws += SW * 2;
    unsigned short* Wvb = (unsigned short*)ws; ws += SW * 2;
    unsigned short* Wpb = (unsigned short*)ws; ws += SW * 2;
    unsigned short* qb  = (unsigned short*)ws; ws += SX * 2;
    unsigned short* kb  = (unsigned short*)ws; ws += SX * 2;
    unsigned short* vtb = (unsigned short*)ws; ws += SX * 2;  // V^T per head [b][h][d][t]
    unsigned short* yb  = (unsigned short*)ws; ws += SX * 2;

    cvt_bf16<<<(int)(SX / 4 / 256), 256, 0, stream>>>(x,  xb,  (int)(SX / 4));
    cvt_bf16<<<(int)(SW / 4 / 256), 256, 0, stream>>>(Wq, Wqb, (int)(SW / 4));
    cvt_bf16<<<(int)(SW / 4 / 256), 256, 0, stream>>>(Wk, Wkb, (int)(SW / 4));
    cvt_bf16<<<(int)(SW / 4 / 256), 256, 0, stream>>>(Wv, Wvb, (int)(SW / 4));
    cvt_bf16<<<(int)(SW / 4 / 256), 256, 0, stream>>>(Wp, Wpb, (int)(SW / 4));

    dim3 gg(64, 8);  // M/128, N/128
    gemm_bt<1><<<gg, 256, 0, stream>>>(xb, Wqb, bq, qb, 8192, 1024, 1024, 0.125f);  // Q pre-scaled
    gemm_bt<1><<<gg, 256, 0, stream>>>(xb, Wkb, bk, kb, 8192, 1024, 1024, 1.0f);
    gemm_bt<2><<<gg, 256, 0, stream>>>(xb, Wvb, bv, vtb, 8192, 1024, 1024, 1.0f);   // writes V^T

    attn_fwd2<<<dim3(T_SEQ / 64, NHEAD, NB), 256, 0, stream>>>(qb, kb, vtb, yb);

    gemm_bt<0><<<gg, 256, 0, stream>>>(yb, Wpb, bp, d_out, 8192, 1024, 1024, 1.0f);
}

// Round 3
// 284.046 us; speedup vs baseline: 1.3933x; 1.3433x over previous
//
#include <hip/hip_runtime.h>

typedef __attribute__((ext_vector_type(8))) short short8;
typedef __attribute__((ext_vector_type(4))) float f32x4;
typedef __attribute__((ext_vector_type(4))) unsigned short u16x4;
typedef __attribute__((ext_vector_type(4))) float float4v;

#define AS1 __attribute__((address_space(1)))
#define AS3 __attribute__((address_space(3)))

#define T_SEQ 2048
#define C_EMB 1024
#define NHEAD 16
#define NB    4

__device__ __forceinline__ unsigned short f2bf(float f) {
    union { float f; unsigned u; } cv; cv.f = f;
    unsigned u = cv.u;
    unsigned r = (u + 0x7FFFu + ((u >> 16) & 1u)) >> 16;
    return (unsigned short)r;
}

__device__ __forceinline__ void async_load16(const void* g, void* l) {
    __builtin_amdgcn_global_load_lds((const AS1 unsigned*)g, (AS3 unsigned*)l, 16, 0, 0);
}

// ---------------- f32 -> bf16 convert ----------------
__global__ void cvt_bf16(const float* __restrict__ in, unsigned short* __restrict__ out, int n4) {
    int i = blockIdx.x * blockDim.x + threadIdx.x;
    if (i >= n4) return;
    float4v v = ((const float4v*)in)[i];
    u16x4 o;
    o[0] = f2bf(v[0]); o[1] = f2bf(v[1]); o[2] = f2bf(v[2]); o[3] = f2bf(v[3]);
    ((u16x4*)out)[i] = o;
}

// ---------------- GEMM: C[M,N] = A[M,K] * B[N,K]^T + bias ----------------
// MODE 0: f32 row-major out. MODE 1: bf16 row-major out (scaled).
// MODE 2: bf16 out transposed per-head: vt[((rr>>11)*1024 + cc)*2048 + (rr&2047)]
template<int MODE>
__global__ void gemm_bt(const unsigned short* __restrict__ A,
                        const unsigned short* __restrict__ B,
                        const float* __restrict__ bias,
                        void* __restrict__ Cout,
                        int M, int N, int K, float scale) {
    __shared__ __align__(16) unsigned short As[128 * 32];
    __shared__ __align__(16) unsigned short Bs[128 * 32];
    const int tid  = threadIdx.x;
    const int wid  = tid >> 6;
    const int lane = tid & 63;
    const int lg = lane >> 4, lr = lane & 15;
    const int wr = wid >> 1, wc = wid & 1;
    const int m0 = blockIdx.x * 128;
    const int n0 = blockIdx.y * 128;

    f32x4 acc[4][4] = {};

    for (int kt = 0; kt < K; kt += 32) {
        #pragma unroll
        for (int r = 0; r < 2; ++r) {
            int cb = r * 4 + wid;            // chunk-block 0..7 (1KB each)
            int chunk = cb * 64 + lane;      // 0..511, 8 elems each
            int row = chunk >> 2;            // 0..127
            int col = (chunk & 3) * 8;       // 0,8,16,24
            async_load16(&A[(size_t)(m0 + row) * K + kt + col], (char*)As + cb * 1024);
            async_load16(&B[(size_t)(n0 + row) * K + kt + col], (char*)Bs + cb * 1024);
        }
        __syncthreads();
        short8 af[4], bfr[4];
        #pragma unroll
        for (int m = 0; m < 4; ++m)
            af[m] = *(const short8*)&As[(wr * 64 + m * 16 + lr) * 32 + lg * 8];
        #pragma unroll
        for (int n = 0; n < 4; ++n)
            bfr[n] = *(const short8*)&Bs[(wc * 64 + n * 16 + lr) * 32 + lg * 8];
        #pragma unroll
        for (int m = 0; m < 4; ++m)
            #pragma unroll
            for (int n = 0; n < 4; ++n)
                acc[m][n] = __builtin_amdgcn_mfma_f32_16x16x32_bf16(af[m], bfr[n], acc[m][n], 0, 0, 0);
        __syncthreads();
    }

    #pragma unroll
    for (int n = 0; n < 4; ++n) {
        int cc = n0 + wc * 64 + n * 16 + lr;
        float bv = bias[cc];
        #pragma unroll
        for (int m = 0; m < 4; ++m) {
            int rr0 = m0 + wr * 64 + m * 16 + lg * 4;
            if (MODE == 2) {
                u16x4 pk;
                #pragma unroll
                for (int r = 0; r < 4; ++r)
                    pk[r] = f2bf((acc[m][n][r] + bv) * scale);
                size_t idx = ((size_t)(rr0 >> 11) * 1024 + cc) * 2048 + (rr0 & 2047);
                *(u16x4*)&((unsigned short*)Cout)[idx] = pk;
            } else {
                #pragma unroll
                for (int r = 0; r < 4; ++r) {
                    float val = (acc[m][n][r] + bv) * scale;
                    if (MODE == 1)
                        ((unsigned short*)Cout)[(size_t)(rr0 + r) * N + cc] = f2bf(val);
                    else
                        ((float*)Cout)[(size_t)(rr0 + r) * N + cc] = val;
                }
            }
        }
    }
}

// ---------------- flash attention (causal) ----------------
// 4 waves x 16 q-rows, KVBLK=64. Swapped QK^T (lane owns q = qw0+lr), exp2 domain.
// K double-buffered in LDS (1 barrier/tile), V prefetched to regs from V^T global.
// Each block does q-groups {x, 31-x} -> uniform 33 tiles (causal load balance).
__global__ __launch_bounds__(256, 4) void attn_fwd3(const unsigned short* __restrict__ Q,
                                                    const unsigned short* __restrict__ Kg,
                                                    const unsigned short* __restrict__ Vt,
                                                    unsigned short* __restrict__ Y) {
    __shared__ __align__(16) unsigned short Ks[2][64 * 64];   // 2 x 8KB, swizzled
    __shared__ __align__(16) unsigned short Pl[4][16 * 64];   // 2KB per wave, swizzled

    const int tid  = threadIdx.x;
    const int w    = tid >> 6;
    const int lane = tid & 63;
    const int lg = lane >> 4, lr = lane & 15;
    const int h   = blockIdx.y;
    const int b   = blockIdx.z;

    const size_t rowbase = ((size_t)b * T_SEQ) * C_EMB + (size_t)h * 64;   // Q,K,Y
    const size_t vtbase  = ((size_t)b * 1024 + (size_t)h * 64) * T_SEQ;    // Vt [d][t]

    // staging lane geometry (pre-swizzled global source, linear LDS dest)
    const int srow = lane >> 3;                  // row 0..7 within 8-row chunk
    const int scol = ((lane & 7) ^ srow) * 8;    // swizzled column element

    unsigned short* Plw = &Pl[w][0];

    #pragma unroll 1
    for (int pair = 0; pair < 2; ++pair) {
        const int grp = pair ? (31 - blockIdx.x) : blockIdx.x;
        const int q0  = grp * 64;
        const int qw0 = q0 + w * 16;
        const int ntiles = grp + 1;

        short8 qf[2];
        #pragma unroll
        for (int s = 0; s < 2; ++s)
            qf[s] = *(const short8*)&Q[rowbase + (size_t)(qw0 + lr) * C_EMB + s * 32 + lg * 8];

        f32x4 o[4] = {};
        float mrun = -1e30f, lrun = 0.0f;

        __syncthreads();   // protect Ks[0] against readers from previous pair
        // prologue: stage K tile 0 -> buf 0
        #pragma unroll
        for (int i = 0; i < 2; ++i) {
            int cb = w * 2 + i;
            async_load16(&Kg[rowbase + (size_t)(cb * 8 + srow) * C_EMB + scol],
                         (char*)Ks[0] + cb * 1024);
        }

        #pragma unroll 1
        for (int t = 0; t < ntiles; ++t) {
            const int kv0 = t * 64;
            const int cur = t & 1, nxt = cur ^ 1;
            __syncthreads();   // K[t] ready (vmcnt drain); buf[nxt] free to overwrite

            // ---- V prefetch (issued BEFORE next K stage: PV waits vmcnt(2) only) ----
            short8 vf[4][2];
            #pragma unroll
            for (int g = 0; g < 4; ++g)
                #pragma unroll
                for (int kc = 0; kc < 2; ++kc)
                    vf[g][kc] = *(const short8*)&Vt[vtbase + (size_t)(g * 16 + lr) * T_SEQ +
                                                    kv0 + kc * 32 + lg * 8];
            // ---- stage next K tile into other buffer ----
            if (t + 1 < ntiles) {
                #pragma unroll
                for (int i = 0; i < 2; ++i) {
                    int cb = w * 2 + i;
                    async_load16(&Kg[rowbase + (size_t)(kv0 + 64 + cb * 8 + srow) * C_EMB + scol],
                                 (char*)Ks[nxt] + cb * 1024);
                }
            }

            // ---- S^T = K * Q^T ----
            f32x4 sa[4] = {};
            #pragma unroll
            for (int kblk = 0; kblk < 4; ++kblk) {
                int row = kblk * 16 + lr;
                #pragma unroll
                for (int s = 0; s < 2; ++s) {
                    short8 kf = *(const short8*)((const char*)Ks[cur] + row * 128 +
                                                 ((s * 64 + lg * 16) ^ ((lr & 7) << 4)));
                    sa[kblk] = __builtin_amdgcn_mfma_f32_16x16x32_bf16(kf, qf[s], sa[kblk], 0, 0, 0);
                }
            }

            // ---- lane-local online softmax (log2 domain; lane owns q = qw0+lr) ----
            float sv[16];
            #pragma unroll
            for (int kblk = 0; kblk < 4; ++kblk)
                #pragma unroll
                for (int r = 0; r < 4; ++r)
                    sv[kblk * 4 + r] = sa[kblk][r];
            if (kv0 + 63 > qw0) {   // wave-uniform: only diagonal tile pays
                const int qi = qw0 + lr;
                #pragma unroll
                for (int kblk = 0; kblk < 4; ++kblk)
                    #pragma unroll
                    for (int r = 0; r < 4; ++r) {
                        int ki = kv0 + kblk * 16 + lg * 4 + r;
                        if (ki > qi) sv[kblk * 4 + r] = -1e30f;
                    }
            }
            float tmax = sv[0];
            #pragma unroll
            for (int i = 1; i < 16; ++i) tmax = fmaxf(tmax, sv[i]);
            tmax = fmaxf(tmax, __shfl_xor(tmax, 16));
            tmax = fmaxf(tmax, __shfl_xor(tmax, 32));
            float mn  = fmaxf(mrun, tmax);
            float scl = exp2f(mrun - mn);
            mrun = mn;
            float rs = 0.0f;
            #pragma unroll
            for (int i = 0; i < 16; ++i) { float p = exp2f(sv[i] - mn); sv[i] = p; rs += p; }
            rs += __shfl_xor(rs, 16);
            rs += __shfl_xor(rs, 32);
            lrun = lrun * scl + rs;
            float scl4[4];
            #pragma unroll
            for (int r = 0; r < 4; ++r) scl4[r] = __shfl(scl, lg * 4 + r);
            #pragma unroll
            for (int g = 0; g < 4; ++g)
                #pragma unroll
                for (int r = 0; r < 4; ++r) o[g][r] *= scl4[r];

            // ---- P^T -> Pl as [q=lr][k] (swizzled), cvt_pk packed b32 writes ----
            #pragma unroll
            for (int kblk = 0; kblk < 4; ++kblk)
                #pragma unroll
                for (int j = 0; j < 2; ++j) {
                    unsigned pk;
                    asm("v_cvt_pk_bf16_f32 %0, %1, %2"
                        : "=v"(pk) : "v"(sv[kblk * 4 + 2 * j]), "v"(sv[kblk * 4 + 2 * j + 1]));
                    *(unsigned*)((char*)Plw + lr * 128 +
                                 ((kblk * 32 + lg * 8 + j * 4) ^ ((lr & 7) << 4))) = pk;
                }
            // ---- read P A-frags (same wave: no barrier needed) ----
            short8 pf[2];
            #pragma unroll
            for (int kc = 0; kc < 2; ++kc)
                pf[kc] = *(const short8*)((const char*)Plw + lr * 128 +
                                          ((kc * 64 + lg * 16) ^ ((lr & 7) << 4)));
            // ---- PV ----
            #pragma unroll
            for (int g = 0; g < 4; ++g)
                #pragma unroll
                for (int kc = 0; kc < 2; ++kc)
                    o[g] = __builtin_amdgcn_mfma_f32_16x16x32_bf16(pf[kc], vf[g][kc], o[g], 0, 0, 0);
        }

        // ---- epilogue: O rows are q = qw0 + lg*4 + r ----
        float l4[4];
        #pragma unroll
        for (int r = 0; r < 4; ++r) l4[r] = __shfl(lrun, lg * 4 + r);
        #pragma unroll
        for (int g = 0; g < 4; ++g)
            #pragma unroll
            for (int r = 0; r < 4; ++r)
                Y[rowbase + (size_t)(qw0 + lg * 4 + r) * C_EMB + g * 16 + lr] =
                    f2bf(o[g][r] / l4[r]);
    }
}

// ---------------- launcher ----------------
extern "C" void kernel_launch(void* const* d_in, const int* in_sizes, int n_in,
                              void* d_out, int out_size, void* d_ws, size_t ws_size,
                              hipStream_t stream) {
    const float* x  = (const float*)d_in[0];
    const float* Wk = (const float*)d_in[1];
    const float* bk = (const float*)d_in[2];
    const float* Wq = (const float*)d_in[3];
    const float* bq = (const float*)d_in[4];
    const float* Wv = (const float*)d_in[5];
    const float* bv = (const float*)d_in[6];
    const float* Wp = (const float*)d_in[7];
    const float* bp = (const float*)d_in[8];

    const size_t SX = (size_t)8192 * 1024;  // activation element count
    const size_t SW = (size_t)1024 * 1024;  // weight element count

    char* ws = (char*)d_ws;
    unsigned short* xb  = (unsigned short*)ws; ws += SX * 2;
    unsigned short* Wqb = (unsigned short*)ws; ws += SW * 2;
    unsigned short* Wkb = (unsigned short*)ws; ws += SW * 2;
    unsigned short* Wvb = (unsigned short*)ws; ws += SW * 2;
    unsigned short* Wpb = (unsigned short*)ws; ws += SW * 2;
    unsigned short* qb  = (unsigned short*)ws; ws += SX * 2;
    unsigned short* kb  = (unsigned short*)ws; ws += SX * 2;
    unsigned short* vtb = (unsigned short*)ws; ws += SX * 2;  // V^T per head [b][h][d][t]
    unsigned short* yb  = (unsigned short*)ws; ws += SX * 2;

    cvt_bf16<<<(int)(SX / 4 / 256), 256, 0, stream>>>(x,  xb,  (int)(SX / 4));
    cvt_bf16<<<(int)(SW / 4 / 256), 256, 0, stream>>>(Wq, Wqb, (int)(SW / 4));
    cvt_bf16<<<(int)(SW / 4 / 256), 256, 0, stream>>>(Wk, Wkb, (int)(SW / 4));
    cvt_bf16<<<(int)(SW / 4 / 256), 256, 0, stream>>>(Wv, Wvb, (int)(SW / 4));
    cvt_bf16<<<(int)(SW / 4 / 256), 256, 0, stream>>>(Wp, Wpb, (int)(SW / 4));

    dim3 gg(64, 8);  // M/128, N/128
    // Q pre-scaled by 0.125*log2(e) -> softmax in exp2 domain
    gemm_bt<1><<<gg, 256, 0, stream>>>(xb, Wqb, bq, qb, 8192, 1024, 1024, 0.18033688f);
    gemm_bt<1><<<gg, 256, 0, stream>>>(xb, Wkb, bk, kb, 8192, 1024, 1024, 1.0f);
    gemm_bt<2><<<gg, 256, 0, stream>>>(xb, Wvb, bv, vtb, 8192, 1024, 1024, 1.0f);   // writes V^T

    attn_fwd3<<<dim3(16, NHEAD, NB), 256, 0, stream>>>(qb, kb, vtb, yb);

    gemm_bt<0><<<gg, 256, 0, stream>>>(yb, Wpb, bp, d_out, 8192, 1024, 1024, 1.0f);
}

// Round 4
// 267.522 us; speedup vs baseline: 1.4794x; 1.0618x over previous
//
#include <hip/hip_runtime.h>

typedef __attribute__((ext_vector_type(8))) short short8;
typedef __attribute__((ext_vector_type(4))) float f32x4;
typedef __attribute__((ext_vector_type(4))) unsigned short u16x4;
typedef __attribute__((ext_vector_type(4))) float float4v;

#define AS1 __attribute__((address_space(1)))
#define AS3 __attribute__((address_space(3)))

#define T_SEQ 2048
#define C_EMB 1024
#define NHEAD 16
#define NB    4
#define SCL_Q 0.18033688f   // 0.125 * log2(e)

__device__ __forceinline__ unsigned short f2bf(float f) {
    union { float f; unsigned u; } cv; cv.f = f;
    unsigned u = cv.u;
    unsigned r = (u + 0x7FFFu + ((u >> 16) & 1u)) >> 16;
    return (unsigned short)r;
}

__device__ __forceinline__ void async_load16(const void* g, void* l) {
    __builtin_amdgcn_global_load_lds((const AS1 unsigned*)g, (AS3 unsigned*)l, 16, 0, 0);
}

// ---------------- f32 -> bf16 convert ----------------
__global__ void cvt_bf16(const float* __restrict__ in, unsigned short* __restrict__ out, int n4) {
    int i = blockIdx.x * blockDim.x + threadIdx.x;
    if (i >= n4) return;
    float4v v = ((const float4v*)in)[i];
    u16x4 o;
    o[0] = f2bf(v[0]); o[1] = f2bf(v[1]); o[2] = f2bf(v[2]); o[3] = f2bf(v[3]);
    ((u16x4*)out)[i] = o;
}

// ---------------- fused QKV GEMM: [8192,1024] x [3072,1024]^T ----------------
// grid (24, 64): x = n-block (B panel), y = m-block (A panel) -> consecutive
// blocks share the A panel. Epilogue select is block-uniform (1024 % 128 == 0):
//   n0 < 1024 -> Q (bf16 row-major, pre-scaled by SCL_Q)
//   n0 < 2048 -> K (bf16 row-major)
//   else      -> V^T per head: vt[((rr>>11)*1024 + cc)*2048 + (rr&2047)]
__global__ void gemm_qkv(const unsigned short* __restrict__ A,
                         const unsigned short* __restrict__ W,
                         const float* __restrict__ bq,
                         const float* __restrict__ bk,
                         const float* __restrict__ bv,
                         unsigned short* __restrict__ Qo,
                         unsigned short* __restrict__ Ko,
                         unsigned short* __restrict__ Vt) {
    __shared__ __align__(16) unsigned short As[128 * 32];
    __shared__ __align__(16) unsigned short Bs[128 * 32];
    const int tid  = threadIdx.x;
    const int wid  = tid >> 6;
    const int lane = tid & 63;
    const int lg = lane >> 4, lr = lane & 15;
    const int wr = wid >> 1, wc = wid & 1;
    const int n0 = blockIdx.x * 128;
    const int m0 = blockIdx.y * 128;
    const int K = 1024;

    f32x4 acc[4][4] = {};

    for (int kt = 0; kt < K; kt += 32) {
        #pragma unroll
        for (int r = 0; r < 2; ++r) {
            int cb = r * 4 + wid;
            int chunk = cb * 64 + lane;
            int row = chunk >> 2;
            int col = (chunk & 3) * 8;
            async_load16(&A[(size_t)(m0 + row) * K + kt + col], (char*)As + cb * 1024);
            async_load16(&W[(size_t)(n0 + row) * K + kt + col], (char*)Bs + cb * 1024);
        }
        __syncthreads();
        short8 af[4], bfr[4];
        #pragma unroll
        for (int m = 0; m < 4; ++m)
            af[m] = *(const short8*)&As[(wr * 64 + m * 16 + lr) * 32 + lg * 8];
        #pragma unroll
        for (int n = 0; n < 4; ++n)
            bfr[n] = *(const short8*)&Bs[(wc * 64 + n * 16 + lr) * 32 + lg * 8];
        #pragma unroll
        for (int m = 0; m < 4; ++m)
            #pragma unroll
            for (int n = 0; n < 4; ++n)
                acc[m][n] = __builtin_amdgcn_mfma_f32_16x16x32_bf16(af[m], bfr[n], acc[m][n], 0, 0, 0);
        __syncthreads();
    }

    const int sel = n0 >> 10;                       // 0=Q 1=K 2=V (block-uniform)
    const int nl0 = n0 & 1023;
    const float* bias = (sel == 0) ? bq : (sel == 1) ? bk : bv;
    const float scale = (sel == 0) ? SCL_Q : 1.0f;

    #pragma unroll
    for (int n = 0; n < 4; ++n) {
        int cc = nl0 + wc * 64 + n * 16 + lr;       // 0..1023 within target
        float bvv = bias[cc];
        #pragma unroll
        for (int m = 0; m < 4; ++m) {
            int rr0 = m0 + wr * 64 + m * 16 + lg * 4;
            u16x4 pk;
            #pragma unroll
            for (int r = 0; r < 4; ++r)
                pk[r] = f2bf((acc[m][n][r] + bvv) * scale);
            if (sel == 2) {
                size_t idx = ((size_t)(rr0 >> 11) * 1024 + cc) * 2048 + (rr0 & 2047);
                *(u16x4*)&Vt[idx] = pk;
            } else {
                unsigned short* out = (sel == 0) ? Qo : Ko;
                #pragma unroll
                for (int r = 0; r < 4; ++r)
                    out[(size_t)(rr0 + r) * 1024 + cc] = pk[r];
            }
        }
    }
}

// ---------------- proj GEMM: C[M,N] = A[M,K]*B[N,K]^T + bias (f32 out) ----------------
__global__ void gemm_proj(const unsigned short* __restrict__ A,
                          const unsigned short* __restrict__ B,
                          const float* __restrict__ bias,
                          float* __restrict__ Cout,
                          int M, int N, int K) {
    __shared__ __align__(16) unsigned short As[128 * 32];
    __shared__ __align__(16) unsigned short Bs[128 * 32];
    const int tid  = threadIdx.x;
    const int wid  = tid >> 6;
    const int lane = tid & 63;
    const int lg = lane >> 4, lr = lane & 15;
    const int wr = wid >> 1, wc = wid & 1;
    const int n0 = blockIdx.x * 128;
    const int m0 = blockIdx.y * 128;

    f32x4 acc[4][4] = {};

    for (int kt = 0; kt < K; kt += 32) {
        #pragma unroll
        for (int r = 0; r < 2; ++r) {
            int cb = r * 4 + wid;
            int chunk = cb * 64 + lane;
            int row = chunk >> 2;
            int col = (chunk & 3) * 8;
            async_load16(&A[(size_t)(m0 + row) * K + kt + col], (char*)As + cb * 1024);
            async_load16(&B[(size_t)(n0 + row) * K + kt + col], (char*)Bs + cb * 1024);
        }
        __syncthreads();
        short8 af[4], bfr[4];
        #pragma unroll
        for (int m = 0; m < 4; ++m)
            af[m] = *(const short8*)&As[(wr * 64 + m * 16 + lr) * 32 + lg * 8];
        #pragma unroll
        for (int n = 0; n < 4; ++n)
            bfr[n] = *(const short8*)&Bs[(wc * 64 + n * 16 + lr) * 32 + lg * 8];
        #pragma unroll
        for (int m = 0; m < 4; ++m)
            #pragma unroll
            for (int n = 0; n < 4; ++n)
                acc[m][n] = __builtin_amdgcn_mfma_f32_16x16x32_bf16(af[m], bfr[n], acc[m][n], 0, 0, 0);
        __syncthreads();
    }

    #pragma unroll
    for (int n = 0; n < 4; ++n) {
        int cc = n0 + wc * 64 + n * 16 + lr;
        float bvv = bias[cc];
        #pragma unroll
        for (int m = 0; m < 4; ++m) {
            int rr0 = m0 + wr * 64 + m * 16 + lg * 4;
            #pragma unroll
            for (int r = 0; r < 4; ++r)
                Cout[(size_t)(rr0 + r) * N + cc] = acc[m][n][r] + bvv;
        }
    }
}

// ---------------- flash attention (causal) ----------------
// 4 waves x 16 q-rows, KVBLK=64, swapped QK^T, exp2 domain, K dbuf, V^T prefetch.
// 1D grid 1024 with XCD swizzle: all 16 q-pair blocks of one (b,h) land on the
// SAME XCD (bid = slot*8 + ((h+16b)&7)) so K/V staging hits that XCD's L2.
// Each block does q-groups {x, 31-x} -> uniform 33 tiles.
__global__ __launch_bounds__(256, 4) void attn_fwd4(const unsigned short* __restrict__ Q,
                                                    const unsigned short* __restrict__ Kg,
                                                    const unsigned short* __restrict__ Vt,
                                                    unsigned short* __restrict__ Y) {
    __shared__ __align__(16) unsigned short Ks[2][64 * 64];   // 2 x 8KB, swizzled
    __shared__ __align__(16) unsigned short Pl[4][16 * 64];   // 2KB per wave, swizzled

    const int bid  = blockIdx.x;            // 0..1023
    const int xcd  = bid & 7;
    const int slot = bid >> 3;              // 0..127
    const int qpair = slot & 15;            // 0..15
    const int bh   = (slot >> 4) * 8 + xcd; // 0..63
    const int h    = bh & 15;
    const int b    = bh >> 4;

    const int tid  = threadIdx.x;
    const int w    = tid >> 6;
    const int lane = tid & 63;
    const int lg = lane >> 4, lr = lane & 15;

    const size_t rowbase = ((size_t)b * T_SEQ) * C_EMB + (size_t)h * 64;   // Q,K,Y
    const size_t vtbase  = ((size_t)b * 1024 + (size_t)h * 64) * T_SEQ;    // Vt [d][t]

    const int srow = lane >> 3;
    const int scol = ((lane & 7) ^ srow) * 8;

    unsigned short* Plw = &Pl[w][0];

    #pragma unroll 1
    for (int pair = 0; pair < 2; ++pair) {
        const int grp = pair ? (31 - qpair) : qpair;
        const int q0  = grp * 64;
        const int qw0 = q0 + w * 16;
        const int ntiles = grp + 1;

        short8 qf[2];
        #pragma unroll
        for (int s = 0; s < 2; ++s)
            qf[s] = *(const short8*)&Q[rowbase + (size_t)(qw0 + lr) * C_EMB + s * 32 + lg * 8];

        f32x4 o[4] = {};
        float mrun = -1e30f, lrun = 0.0f;

        __syncthreads();   // protect Ks[0] against readers from previous pair
        #pragma unroll
        for (int i = 0; i < 2; ++i) {
            int cb = w * 2 + i;
            async_load16(&Kg[rowbase + (size_t)(cb * 8 + srow) * C_EMB + scol],
                         (char*)Ks[0] + cb * 1024);
        }

        #pragma unroll 1
        for (int t = 0; t < ntiles; ++t) {
            const int kv0 = t * 64;
            const int cur = t & 1, nxt = cur ^ 1;
            __syncthreads();   // K[t] ready; buf[nxt] free

            // V prefetch (issued before next K stage)
            short8 vf[4][2];
            #pragma unroll
            for (int g = 0; g < 4; ++g)
                #pragma unroll
                for (int kc = 0; kc < 2; ++kc)
                    vf[g][kc] = *(const short8*)&Vt[vtbase + (size_t)(g * 16 + lr) * T_SEQ +
                                                    kv0 + kc * 32 + lg * 8];
            // stage next K tile
            if (t + 1 < ntiles) {
                #pragma unroll
                for (int i = 0; i < 2; ++i) {
                    int cb = w * 2 + i;
                    async_load16(&Kg[rowbase + (size_t)(kv0 + 64 + cb * 8 + srow) * C_EMB + scol],
                                 (char*)Ks[nxt] + cb * 1024);
                }
            }

            // S^T = K * Q^T
            f32x4 sa[4] = {};
            #pragma unroll
            for (int kblk = 0; kblk < 4; ++kblk) {
                int row = kblk * 16 + lr;
                #pragma unroll
                for (int s = 0; s < 2; ++s) {
                    short8 kf = *(const short8*)((const char*)Ks[cur] + row * 128 +
                                                 ((s * 64 + lg * 16) ^ ((lr & 7) << 4)));
                    sa[kblk] = __builtin_amdgcn_mfma_f32_16x16x32_bf16(kf, qf[s], sa[kblk], 0, 0, 0);
                }
            }

            // lane-local online softmax (lane owns q = qw0+lr), exp2 domain
            float sv[16];
            #pragma unroll
            for (int kblk = 0; kblk < 4; ++kblk)
                #pragma unroll
                for (int r = 0; r < 4; ++r)
                    sv[kblk * 4 + r] = sa[kblk][r];
            if (kv0 + 63 > qw0) {
                const int qi = qw0 + lr;
                #pragma unroll
                for (int kblk = 0; kblk < 4; ++kblk)
                    #pragma unroll
                    for (int r = 0; r < 4; ++r) {
                        int ki = kv0 + kblk * 16 + lg * 4 + r;
                        if (ki > qi) sv[kblk * 4 + r] = -1e30f;
                    }
            }
            float tmax = sv[0];
            #pragma unroll
            for (int i = 1; i < 16; ++i) tmax = fmaxf(tmax, sv[i]);
            tmax = fmaxf(tmax, __shfl_xor(tmax, 16));
            tmax = fmaxf(tmax, __shfl_xor(tmax, 32));
            float mn  = fmaxf(mrun, tmax);
            float scl = exp2f(mrun - mn);
            mrun = mn;
            float rs = 0.0f;
            #pragma unroll
            for (int i = 0; i < 16; ++i) { float p = exp2f(sv[i] - mn); sv[i] = p; rs += p; }
            rs += __shfl_xor(rs, 16);
            rs += __shfl_xor(rs, 32);
            lrun = lrun * scl + rs;
            float scl4[4];
            #pragma unroll
            for (int r = 0; r < 4; ++r) scl4[r] = __shfl(scl, lg * 4 + r);
            #pragma unroll
            for (int g = 0; g < 4; ++g)
                #pragma unroll
                for (int r = 0; r < 4; ++r) o[g][r] *= scl4[r];

            // P^T -> Pl (swizzled, cvt_pk packed writes)
            #pragma unroll
            for (int kblk = 0; kblk < 4; ++kblk)
                #pragma unroll
                for (int j = 0; j < 2; ++j) {
                    unsigned pk;
                    asm("v_cvt_pk_bf16_f32 %0, %1, %2"
                        : "=v"(pk) : "v"(sv[kblk * 4 + 2 * j]), "v"(sv[kblk * 4 + 2 * j + 1]));
                    *(unsigned*)((char*)Plw + lr * 128 +
                                 ((kblk * 32 + lg * 8 + j * 4) ^ ((lr & 7) << 4))) = pk;
                }
            short8 pf[2];
            #pragma unroll
            for (int kc = 0; kc < 2; ++kc)
                pf[kc] = *(const short8*)((const char*)Plw + lr * 128 +
                                          ((kc * 64 + lg * 16) ^ ((lr & 7) << 4)));
            #pragma unroll
            for (int g = 0; g < 4; ++g)
                #pragma unroll
                for (int kc = 0; kc < 2; ++kc)
                    o[g] = __builtin_amdgcn_mfma_f32_16x16x32_bf16(pf[kc], vf[g][kc], o[g], 0, 0, 0);
        }

        float l4[4];
        #pragma unroll
        for (int r = 0; r < 4; ++r) l4[r] = __shfl(lrun, lg * 4 + r);
        #pragma unroll
        for (int g = 0; g < 4; ++g)
            #pragma unroll
            for (int r = 0; r < 4; ++r)
                Y[rowbase + (size_t)(qw0 + lg * 4 + r) * C_EMB + g * 16 + lr] =
                    f2bf(o[g][r] / l4[r]);
    }
}

// ---------------- launcher ----------------
extern "C" void kernel_launch(void* const* d_in, const int* in_sizes, int n_in,
                              void* d_out, int out_size, void* d_ws, size_t ws_size,
                              hipStream_t stream) {
    const float* x  = (const float*)d_in[0];
    const float* Wk = (const float*)d_in[1];
    const float* bk = (const float*)d_in[2];
    const float* Wq = (const float*)d_in[3];
    const float* bq = (const float*)d_in[4];
    const float* Wv = (const float*)d_in[5];
    const float* bv = (const float*)d_in[6];
    const float* Wp = (const float*)d_in[7];
    const float* bp = (const float*)d_in[8];

    const size_t SX = (size_t)8192 * 1024;
    const size_t SW = (size_t)1024 * 1024;

    char* ws = (char*)d_ws;
    unsigned short* xb   = (unsigned short*)ws; ws += SX * 2;
    unsigned short* Wqkv = (unsigned short*)ws; ws += 3 * SW * 2;  // [Wq;Wk;Wv] rows
    unsigned short* Wpb  = (unsigned short*)ws; ws += SW * 2;
    unsigned short* qb   = (unsigned short*)ws; ws += SX * 2;
    unsigned short* kb   = (unsigned short*)ws; ws += SX * 2;
    unsigned short* vtb  = (unsigned short*)ws; ws += SX * 2;  // V^T per head [b][h][d][t]
    unsigned short* yb   = (unsigned short*)ws; ws += SX * 2;

    cvt_bf16<<<(int)(SX / 4 / 256), 256, 0, stream>>>(x,  xb, (int)(SX / 4));
    cvt_bf16<<<(int)(SW / 4 / 256), 256, 0, stream>>>(Wq, Wqkv,               (int)(SW / 4));
    cvt_bf16<<<(int)(SW / 4 / 256), 256, 0, stream>>>(Wk, Wqkv + SW,          (int)(SW / 4));
    cvt_bf16<<<(int)(SW / 4 / 256), 256, 0, stream>>>(Wv, Wqkv + 2 * SW,      (int)(SW / 4));
    cvt_bf16<<<(int)(SW / 4 / 256), 256, 0, stream>>>(Wp, Wpb,                (int)(SW / 4));

    gemm_qkv<<<dim3(24, 64), 256, 0, stream>>>(xb, Wqkv, bq, bk, bv, qb, kb, vtb);

    attn_fwd4<<<dim3(1024), 256, 0, stream>>>(qb, kb, vtb, yb);

    gemm_proj<<<dim3(8, 64), 256, 0, stream>>>(yb, Wpb, bp, (float*)d_out, 8192, 1024, 1024);
}